// Round 1
// baseline (230.109 us; speedup 1.0000x reference)
//
#include <hip/hip_runtime.h>

// FWHT over last dim (4096) of [8192, 4096] fp32, normalized by 1/64.
// Radix-64 x 64 decomposition: ONE WAVE PER ROW, 64 floats per lane.
//   1) lane l loads x[64l .. 64l+63]            (16 x global_load_dwordx4)
//   2) in-register FWHT-64 over bits 0..5       (384 VALU, LSB-first == reference order)
//   3) LDS transpose: write own row (b128), read own column (b32, 2-way free)
//   4) in-register FWHT-64 over bits 6..11, scale, store contiguous-across-lanes
// No __syncthreads across waves is needed (single-wave workgroup): only a
// waitcnt orders the LDS write->read. Each wave is a fully independent,
// deeply pipelined stream -> latency hiding comes from 9 resident waves/CU
// each with 16 KiB of loads in flight, not from barrier-convoyed blocks.

#define N        4096
#define THREADS  64
#define TSTR     68          // LDS row stride in floats: 64+4 -> rows 16B-aligned,
                             // row starts shift banks by 4 (write quads spread,
                             // column reads land 2 lanes/bank = free)
#define LDS_FLOATS (64 * TSTR)   // 4352 floats = 17408 B -> 9 blocks(waves)/CU

__device__ __forceinline__ void fwht64(float v[64]) {
    // In-place 64-point FWHT, stages LSB->MSB (stride 1,2,4,8,16,32).
    // Identical butterfly form and bit order to the reference recursion,
    // so the fp32 summation tree (and rounding) matches bit-exactly.
#pragma unroll
    for (int s = 1; s < 64; s <<= 1) {
#pragma unroll
        for (int k = 0; k < 64; k++) {
            if ((k & s) == 0) {
                float a = v[k];
                float b = v[k + s];
                v[k]     = a + b;
                v[k + s] = a - b;
            }
        }
    }
}

__global__ __launch_bounds__(THREADS)
void FWHT_83476984365427_kernel(const float* __restrict__ x,
                                float* __restrict__ out,
                                int nrows) {
    __shared__ float tile[LDS_FLOATS];

    const int row = blockIdx.x;
    if (row >= nrows) return;

    const float* __restrict__ xr  = x   + (size_t)row * N;
    float* __restrict__       otr = out + (size_t)row * N;
    const int l = threadIdx.x;   // lane 0..63

    float v[64];

    // ---- Load: lane l owns elements 64l .. 64l+63 (bits 0..5 in-register).
    // 16 dwordx4 per lane; each 64B line is touched only by one lane's
    // back-to-back instructions -> fetched once, remainder L1-served.
    {
        const float4* xv = (const float4*)xr + (size_t)l * 16;
#pragma unroll
        for (int c = 0; c < 16; c++) {
            float4 f = xv[c];
            v[4 * c + 0] = f.x;
            v[4 * c + 1] = f.y;
            v[4 * c + 2] = f.z;
            v[4 * c + 3] = f.w;
        }
    }

    // ---- FWHT over element bits 0..5 (reg index r == element low bits).
    fwht64(v);

    // ---- Transpose via LDS (wave-private tile, no barrier needed).
    // Write own row h=l: addr = l*TSTR + 4c, 16B aligned (TSTR*4 = 272 = 17*16).
    {
        float* dst = &tile[l * TSTR];
#pragma unroll
        for (int c = 0; c < 16; c++) {
            float4 f;
            f.x = v[4 * c + 0];
            f.y = v[4 * c + 1];
            f.z = v[4 * c + 2];
            f.w = v[4 * c + 3];
            *(float4*)(dst + 4 * c) = f;
        }
    }
    __syncthreads();   // single wave: effectively just the lgkmcnt fence

    // Read own column l: v[m] = tile[m][l]. Immediate-offset ds_read_b32;
    // banks = (4m + l) % 32 -> exactly 2 lanes/bank = conflict-free cost.
#pragma unroll
    for (int m = 0; m < 64; m++) v[m] = tile[m * TSTR + l];

    // ---- FWHT over element bits 6..11 (reg index m == element high bits).
    fwht64(v);

    // ---- Scale (exact: 2^-6) and store. Output element = 64m + l:
    // per instruction the wave writes 256 B contiguous = 4 full 64B lines.
    const float scale = 1.0f / 64.0f;
#pragma unroll
    for (int m = 0; m < 64; m++) otr[m * 64 + l] = v[m] * scale;
}

extern "C" void kernel_launch(void* const* d_in, const int* in_sizes, int n_in,
                              void* d_out, int out_size, void* d_ws, size_t ws_size,
                              hipStream_t stream) {
    (void)n_in; (void)d_ws; (void)ws_size; (void)out_size;
    const float* x = (const float*)d_in[0];
    float* out = (float*)d_out;
    const int nrows = in_sizes[0] / N;
    dim3 grid(nrows);
    dim3 block(THREADS);
    FWHT_83476984365427_kernel<<<grid, block, 0, stream>>>(x, out, nrows);
}

// Round 3
// 229.255 us; speedup vs baseline: 1.0037x; 1.0037x over previous
//
#include <hip/hip_runtime.h>

// FWHT over last dim (4096) of [8192, 4096] fp32, normalized by 1/64.
// One wave per row, 64 floats per lane, radix-64 x 64:
//   1) global_load_lds stages the 16 KB row into LDS: 16 instructions, each
//      1024 B wave-contiguous (16 cache lines, fully coalesced). The GLOBAL
//      source address is pre-swizzled per lane so the (linear-write) LDS image
//      carries an XOR chunk swizzle: chunk (hi,c) -> slot hi*16 + (c^(hi&15)).
//   2) lane l reads its row hi=l: 16 x ds_read_b128 (8 lanes/bank-quad = b128
//      data-path floor, conflict-free), fwht64 over bits 0..5 in registers.
//   3) transpose-write into the SAME chunk slots (lane-local overwrite, tile
//      overlays itself -> total LDS exactly 16 KB, 10 waves/CU).
//   4) column read ds_read_b32: bank = permuted 0..63 -> exact 2 lanes/bank
//      (free). fwht64 over bits 6..11, scale, coalesced dword stores.
// Butterfly order LSB->MSB matches the reference recursion's summation tree
// -> absmax 0.0 expected.

#define N        4096
#define THREADS  64
#define LDS_FLOATS 4096      // 16384 B -> 10 single-wave blocks per CU

__device__ __forceinline__ void fwht64(float v[64]) {
    // In-place 64-point FWHT, stages LSB->MSB (stride 1,2,4,8,16,32).
#pragma unroll
    for (int s = 1; s < 64; s <<= 1) {
#pragma unroll
        for (int k = 0; k < 64; k++) {
            if ((k & s) == 0) {
                float a = v[k];
                float b = v[k + s];
                v[k]     = a + b;
                v[k + s] = a - b;
            }
        }
    }
}

__global__ __launch_bounds__(THREADS)
void FWHT_83476984365427_kernel(const float* __restrict__ x,
                                float* __restrict__ out,
                                int nrows) {
    __shared__ float lds[LDS_FLOATS];

    const int row = blockIdx.x;
    if (row >= nrows) return;

    const float* __restrict__ xr  = x   + (size_t)row * N;
    float* __restrict__       otr = out + (size_t)row * N;
    const int l  = threadIdx.x;   // lane 0..63
    const int lh = l >> 4;        // 0..3
    const int ls = l & 15;        // 0..15

    // ---- Stage: 16 x global_load_lds, 16 B/lane, wave-contiguous source
    // within each 16-lane group (256 B segment, permuted inside = still
    // fully coalesced). LDS write is linear: instr i, lane L -> 16B chunk
    // slot 64*i + L. Slot s must hold global chunk (hi = s>>4, c with
    // c ^ (hi&15) = s&15)  ->  hi = 4i + (L>>4), c = (L&15) ^ (hi&15).
#pragma unroll
    for (int i = 0; i < 16; i++) {
        const int hi = 4 * i + lh;
        const int hm = 4 * (i & 3) + lh;      // == hi & 15 (no carry: <= 15)
        const int c  = ls ^ hm;
        const float* src = xr + hi * 64 + c * 4;
        __builtin_amdgcn_global_load_lds(
            (const __attribute__((address_space(1))) void*)src,
            (__attribute__((address_space(3))) void*)(&lds[i * 256]),
            16, 0, 0);
    }
    asm volatile("s_waitcnt vmcnt(0)" ::: "memory");
    __syncthreads();   // single wave: cheap, keeps LDS ordering airtight

    float v[64];

    // ---- Row read: chunk (hi=l, c) lives at lds[l*64 + 4*(c ^ (l&15))].
    {
        const float* rowp = &lds[l * 64];
#pragma unroll
        for (int c = 0; c < 16; c++) {
            float4 f = *(const float4*)(rowp + ((c ^ ls) << 2));
            v[4 * c + 0] = f.x;
            v[4 * c + 1] = f.y;
            v[4 * c + 2] = f.z;
            v[4 * c + 3] = f.w;
        }
    }

    // ---- FWHT over element bits 0..5.
    fwht64(v);

    // ---- Transpose write: same chunk slots (lane-local, overlays stage tile).
    {
        float* rowp = &lds[l * 64];
#pragma unroll
        for (int c = 0; c < 16; c++) {
            float4 f;
            f.x = v[4 * c + 0];
            f.y = v[4 * c + 1];
            f.z = v[4 * c + 2];
            f.w = v[4 * c + 3];
            *(float4*)(rowp + ((c ^ ls) << 2)) = f;
        }
    }
    __syncthreads();

    // ---- Column read: element (m, lane l) sits at
    // lds[m*64 + 4*((l>>2) ^ (m&15)) + (l&3)]. Per instruction (fixed m) the
    // 64 lanes hit 64 distinct dwords mod 64 -> exactly 2 lanes/bank = free.
    {
        const int l2 = l >> 2;
        const int j  = l & 3;
#pragma unroll
        for (int ml = 0; ml < 16; ml++) {
            const int off = ((l2 ^ ml) << 2) + j;
#pragma unroll
            for (int mh = 0; mh < 4; mh++) {
                v[mh * 16 + ml] = lds[(mh * 16 + ml) * 64 + off];
            }
        }
    }

    // ---- FWHT over element bits 6..11.
    fwht64(v);

    // ---- Scale (exact 2^-6) and store: wave writes 256 B contiguous / instr.
    const float scale = 1.0f / 64.0f;
#pragma unroll
    for (int m = 0; m < 64; m++) otr[m * 64 + l] = v[m] * scale;
}

extern "C" void kernel_launch(void* const* d_in, const int* in_sizes, int n_in,
                              void* d_out, int out_size, void* d_ws, size_t ws_size,
                              hipStream_t stream) {
    (void)n_in; (void)d_ws; (void)ws_size; (void)out_size;
    const float* x = (const float*)d_in[0];
    float* out = (float*)d_out;
    const int nrows = in_sizes[0] / N;
    dim3 grid(nrows);
    dim3 block(THREADS);
    FWHT_83476984365427_kernel<<<grid, block, 0, stream>>>(x, out, nrows);
}